// Round 1
// baseline (539.948 us; speedup 1.0000x reference)
//
#include <hip/hip_runtime.h>

// Problem constants
#define DD    64      // D
#define TWOD  128     // 2*D
#define RD    256     // RANK*D

typedef __attribute__((ext_vector_type(8))) short short8;   // 8 bf16 = 4 VGPRs (MFMA A/B frag)
typedef __attribute__((ext_vector_type(4))) float float4v;  // MFMA C/D frag

__device__ __forceinline__ unsigned short f2b(float f) {
    // fp32 -> bf16 round-to-nearest-even
    unsigned u = __builtin_bit_cast(unsigned, f);
    u += 0x7fffu + ((u >> 16) & 1u);
    return (unsigned short)(u >> 16);
}
__device__ __forceinline__ float b2f(unsigned short s) {
    unsigned u = ((unsigned)s) << 16;
    return __builtin_bit_cast(float, u);
}
__device__ __forceinline__ float ftanh(float x) {
    // tanh(x) = 1 - 2/(e^{2x}+1); safe at extremes (exp->inf/0 gives +/-1)
    float e = __expf(2.0f * x);
    return 1.0f - 2.0f / (e + 1.0f);
}

// ---------------------------------------------------------------------------
// Prep: build bf16 weight layouts in d_ws so MFMA B-fragments are contiguous
// 16B reads. B-frag for block (kb,nb): lane reads W[n=nb*16+lane15][k=kb*32+q*8 ..+7]
//   wa [128][64]  = W1            (B of GEMM1: h  = x  @ W1^T)
//   wd [64][128]  = W1^T          (B of GEMM4: dx = da1@ W1)
//   wb [256][128] = W2            (B of GEMM2: a2 = h  @ W2^T)
//   wc [128][256] = W2^T          (B of GEMM3: dh = da2@ W2)
// ---------------------------------------------------------------------------
__global__ void prep_weights(const float* __restrict__ W1, const float* __restrict__ W2,
                             unsigned short* __restrict__ wa, unsigned short* __restrict__ wd,
                             unsigned short* __restrict__ wb, unsigned short* __restrict__ wc) {
    int t = blockIdx.x * blockDim.x + threadIdx.x;
    if (t < 8192) {
        wa[t] = f2b(W1[t]);                  // [128][64] copy
        int c = t >> 7, r = t & 127;         // wd[c][r] = W1[r][c]
        wd[t] = f2b(W1[r * 64 + c]);
    }
    if (t < 32768) {
        wb[t] = f2b(W2[t]);                  // [256][128] copy
        int c = t >> 8, k = t & 255;         // wc[c][k] = W2[k][c]
        wc[t] = f2b(W2[k * 128 + c]);
    }
}

// ---------------------------------------------------------------------------
// Main: one wave (64 threads) per 16-row tile. All 4 GEMMs via
// v_mfma_f32_16x16x32_bf16; activations round-trip LDS (padded to kill bank
// conflicts + keep 16B alignment); weight B-frags stream from global (L2).
// LDS/block ~= 21.0 KB -> 7 blocks/CU.
// ---------------------------------------------------------------------------
__global__ __launch_bounds__(64) void geognn_kernel(
    const float* __restrict__ inp, const float* __restrict__ b1, const float* __restrict__ b2,
    const unsigned short* __restrict__ wa, const unsigned short* __restrict__ wd,
    const unsigned short* __restrict__ wb, const unsigned short* __restrict__ wc,
    float* __restrict__ out) {

    __shared__ float          v_s[16][68];    // v (fp32: feeds y & da2)
    __shared__ unsigned short h_s[16][136];   // h bf16, later overwritten by da1
    __shared__ unsigned short g1_s[16][136];  // 1-h^2 bf16 (computed from fp32 h!)
    __shared__ unsigned short d_s[16][264];   // u bf16, later overwritten by da2

    const int  l   = threadIdx.x;
    const int  l15 = l & 15;
    const int  q   = l >> 4;
    const long row0 = (long)blockIdx.x * 16;

    // bias preload: lane's C-columns are n = nb*16 + l15
    float b1v[8], b2v[16];
#pragma unroll
    for (int nb = 0; nb < 8; ++nb)  b1v[nb] = b1[nb * 16 + l15];
#pragma unroll
    for (int nb = 0; nb < 16; ++nb) b2v[nb] = b2[nb * 16 + l15];

    // stage V tile (coalesced)
#pragma unroll 4
    for (int r = 0; r < 16; ++r)
        v_s[r][l] = inp[(row0 + r) * TWOD + DD + l];

    // GEMM1 A-frags (x) straight from global: A[m=l15][k=kb*32+q*8+j]
    short8 ax[2];
#pragma unroll
    for (int kb = 0; kb < 2; ++kb) {
        const float* p = inp + (row0 + l15) * TWOD + kb * 32 + q * 8;
        short8 a;
#pragma unroll
        for (int j = 0; j < 8; ++j) a[j] = (short)f2b(p[j]);
        ax[kb] = a;
    }

    // ---- GEMM1: h = tanh(x @ W1^T + b1)  (M16 x K64 x N128) ----
#pragma unroll
    for (int nb = 0; nb < 8; ++nb) {
        float4v acc = {0.f, 0.f, 0.f, 0.f};
#pragma unroll
        for (int kb = 0; kb < 2; ++kb) {
            short8 bw = *(const short8*)(wa + (nb * 16 + l15) * DD + kb * 32 + q * 8);
            acc = __builtin_amdgcn_mfma_f32_16x16x32_bf16(ax[kb], bw, acc, 0, 0, 0);
        }
#pragma unroll
        for (int i = 0; i < 4; ++i) {
            int r = q * 4 + i, c = nb * 16 + l15;
            float h = ftanh(acc[i] + b1v[nb]);
            h_s[r][c]  = f2b(h);
            g1_s[r][c] = f2b(1.0f - h * h);
        }
    }
    __syncthreads();   // h_s/g1_s/v_s cross-lane visibility

    // ---- GEMM2: u = tanh(h @ W2^T + b2)  (M16 x K128 x N256), fused y partials ----
    short8 ha[4];
#pragma unroll
    for (int kb = 0; kb < 4; ++kb)
        ha[kb] = *(const short8*)(&h_s[l15][kb * 32 + q * 8]);

    float yp[4] = {0.f, 0.f, 0.f, 0.f};   // y[r=q*4+i][j=l15&3] partials
#pragma unroll
    for (int nb = 0; nb < 16; ++nb) {
        float4v acc = {0.f, 0.f, 0.f, 0.f};
#pragma unroll
        for (int kb = 0; kb < 4; ++kb) {
            short8 bw = *(const short8*)(wb + (nb * 16 + l15) * TWOD + kb * 32 + q * 8);
            acc = __builtin_amdgcn_mfma_f32_16x16x32_bf16(ha[kb], bw, acc, 0, 0, 0);
        }
#pragma unroll
        for (int i = 0; i < 4; ++i) {
            int r = q * 4 + i, n = nb * 16 + l15;
            float u = ftanh(acc[i] + b2v[nb]);
            d_s[r][n] = f2b(u);
            yp[i] += v_s[r][n >> 2] * u;   // n = 4*(n>>2) + (l15&3): j is fixed per lane
        }
    }
    // complete y: reduce over lanes with same l15&3 (within quad -> same rows)
#pragma unroll
    for (int i = 0; i < 4; ++i) {
        yp[i] += __shfl_xor(yp[i], 4, 64);
        yp[i] += __shfl_xor(yp[i], 8, 64);
    }

    // ---- da2 = 2*y_j*v_i*(1-u^2) (overwrite d_s); dv -> out[:,64:] fused ----
#pragma unroll
    for (int nb = 0; nb < 16; ++nb) {
#pragma unroll
        for (int i = 0; i < 4; ++i) {
            int r = q * 4 + i, n = nb * 16 + l15;
            float u  = b2f(d_s[r][n]);
            float vv = v_s[r][n >> 2];
            d_s[r][n] = f2b(2.0f * yp[i] * vv * (1.0f - u * u));
            float p = yp[i] * u;              // y_j * u[4iv+j]
            p += __shfl_xor(p, 1, 64);
            p += __shfl_xor(p, 2, 64);
            if ((l15 & 3) == 0)
                out[(row0 + r) * TWOD + DD + (n >> 2)] = -2.0f * p;  // -dv
        }
    }
    __syncthreads();   // da2 visible for A-frag reads

    // ---- GEMM3: dh = da2 @ W2  (M16 x K256 x N128); da1 = dh*(1-h^2) -> h_s ----
    short8 da[8];
#pragma unroll
    for (int kb = 0; kb < 8; ++kb)
        da[kb] = *(const short8*)(&d_s[l15][kb * 32 + q * 8]);
#pragma unroll
    for (int nb = 0; nb < 8; ++nb) {
        float4v acc = {0.f, 0.f, 0.f, 0.f};
#pragma unroll
        for (int kb = 0; kb < 8; ++kb) {
            short8 bw = *(const short8*)(wc + (nb * 16 + l15) * RD + kb * 32 + q * 8);
            acc = __builtin_amdgcn_mfma_f32_16x16x32_bf16(da[kb], bw, acc, 0, 0, 0);
        }
#pragma unroll
        for (int i = 0; i < 4; ++i) {
            int r = q * 4 + i, c = nb * 16 + l15;
            h_s[r][c] = f2b(acc[i] * b2f(g1_s[r][c]));
        }
    }
    __syncthreads();   // da1 visible

    // ---- GEMM4: dx = da1 @ W1  (M16 x K128 x N64) -> out[:, :64] ----
    short8 dfa[4];
#pragma unroll
    for (int kb = 0; kb < 4; ++kb)
        dfa[kb] = *(const short8*)(&h_s[l15][kb * 32 + q * 8]);
#pragma unroll
    for (int nb = 0; nb < 4; ++nb) {
        float4v acc = {0.f, 0.f, 0.f, 0.f};
#pragma unroll
        for (int kb = 0; kb < 4; ++kb) {
            short8 bw = *(const short8*)(wd + (nb * 16 + l15) * TWOD + kb * 32 + q * 8);
            acc = __builtin_amdgcn_mfma_f32_16x16x32_bf16(dfa[kb], bw, acc, 0, 0, 0);
        }
#pragma unroll
        for (int i = 0; i < 4; ++i)
            out[(row0 + q * 4 + i) * TWOD + nb * 16 + l15] = acc[i];
    }
}

extern "C" void kernel_launch(void* const* d_in, const int* in_sizes, int n_in,
                              void* d_out, int out_size, void* d_ws, size_t ws_size,
                              hipStream_t stream) {
    // inputs: 0=t (unused), 1=input_ (N x 128 f32), 2=W1 (128x64), 3=b1 (128),
    //         4=W2 (256x128), 5=b2 (256)
    const float* inp = (const float*)d_in[1];
    const float* W1  = (const float*)d_in[2];
    const float* b1  = (const float*)d_in[3];
    const float* W2  = (const float*)d_in[4];
    const float* b2  = (const float*)d_in[5];

    unsigned short* wa = (unsigned short*)d_ws;   // 8192  elems @ off 0
    unsigned short* wd = wa + 8192;               // 8192  elems
    unsigned short* wb = wd + 8192;               // 32768 elems
    unsigned short* wc = wb + 32768;              // 32768 elems  (total 160 KB)

    prep_weights<<<128, 256, 0, stream>>>(W1, W2, wa, wd, wb, wc);

    const int rows = in_sizes[1] / TWOD;          // 262144
    geognn_kernel<<<rows / 16, 64, 0, stream>>>(inp, b1, b2, wa, wd, wb, wc,
                                                (float*)d_out);
}

// Round 2
// 485.718 us; speedup vs baseline: 1.1116x; 1.1116x over previous
//
#include <hip/hip_runtime.h>

#define DD    64      // D
#define TWOD  128     // 2*D
#define RD    256     // RANK*D

typedef __attribute__((ext_vector_type(8))) short short8;   // 8 bf16 (MFMA A/B frag)
typedef __attribute__((ext_vector_type(4))) float float4v;  // MFMA C/D frag
typedef unsigned long long ull;

__device__ __forceinline__ unsigned short f2b(float f) {
    unsigned u = __builtin_bit_cast(unsigned, f);
    u += 0x7fffu + ((u >> 16) & 1u);
    return (unsigned short)(u >> 16);
}
__device__ __forceinline__ float b2f(unsigned short s) {
    unsigned u = ((unsigned)s) << 16;
    return __builtin_bit_cast(float, u);
}
__device__ __forceinline__ float ftanh(float x) {
    float e = __expf(2.0f * x);
    return 1.0f - 2.0f / (e + 1.0f);
}
// Single-wave workgroup: DS ops execute in order per wave, so lgkmcnt(0) +
// a compiler memory fence replaces __syncthreads() (no vmcnt(0) drain ->
// global prefetches stay in flight across stage boundaries).
__device__ __forceinline__ void lds_fence() {
    asm volatile("s_waitcnt lgkmcnt(0)" ::: "memory");
}

// ---------------------------------------------------------------------------
// Prep: bf16 weight layouts so MFMA B-frags are contiguous 16B reads.
//   wa [128][64]  = W1      (GEMM1: h  = x  @ W1^T)
//   wd [64][128]  = W1^T    (GEMM4: dx = da1@ W1)
//   wb [256][128] = W2      (GEMM2: u  = h  @ W2^T)
//   wc [128][256] = W2^T    (GEMM3: dh = da2@ W2)
// ---------------------------------------------------------------------------
__global__ void prep_weights(const float* __restrict__ W1, const float* __restrict__ W2,
                             unsigned short* __restrict__ wa, unsigned short* __restrict__ wd,
                             unsigned short* __restrict__ wb, unsigned short* __restrict__ wc) {
    int t = blockIdx.x * blockDim.x + threadIdx.x;
    if (t < 8192) {
        wa[t] = f2b(W1[t]);
        int c = t >> 7, r = t & 127;
        wd[t] = f2b(W1[r * 64 + c]);
    }
    if (t < 32768) {
        wb[t] = f2b(W2[t]);
        int c = t >> 8, k = t & 255;
        wc[t] = f2b(W2[k * 128 + c]);
    }
}

// ---------------------------------------------------------------------------
// One wave per 16-row tile. LDS 17408 B -> 9 blocks/CU. No s_barrier.
// ---------------------------------------------------------------------------
__global__ __launch_bounds__(64, 3) void geognn_kernel(
    const float* __restrict__ inp, const float* __restrict__ b1, const float* __restrict__ b2,
    const unsigned short* __restrict__ wa, const unsigned short* __restrict__ wd,
    const unsigned short* __restrict__ wb, const unsigned short* __restrict__ wc,
    float* __restrict__ out) {

    __shared__ float          v_s[16][68];    // v fp32
    __shared__ unsigned short h_s[16][136];   // h bf16, later da1
    __shared__ unsigned short d_s[16][264];   // u bf16, later da2 (stride 264: 8B-aligned rows)
    __shared__ float4v        y_s[16];        // y per row (4 floats)

    const int  l   = threadIdx.x;
    const int  l15 = l & 15;
    const int  q   = l >> 4;
    const long row0 = (long)blockIdx.x * 16;

    // ---- stage V tile (coalesced) ----
#pragma unroll
    for (int r = 0; r < 16; ++r)
        v_s[r][l] = inp[(row0 + r) * TWOD + DD + l];

    // ---- x A-frags from global: A[m=l15][k=kb*32+q*8+j] ----
    short8 ax[2];
#pragma unroll
    for (int kb = 0; kb < 2; ++kb) {
        const float4v* p = (const float4v*)(inp + (row0 + l15) * TWOD + kb * 32 + q * 8);
        float4v f0 = p[0], f1 = p[1];
        short8 a;
        a[0] = (short)f2b(f0.x); a[1] = (short)f2b(f0.y);
        a[2] = (short)f2b(f0.z); a[3] = (short)f2b(f0.w);
        a[4] = (short)f2b(f1.x); a[5] = (short)f2b(f1.y);
        a[6] = (short)f2b(f1.z); a[7] = (short)f2b(f1.w);
        ax[kb] = a;
    }

    // biases (lane's C-columns: n = nb*16 + l15)
    float b1v[8];
#pragma unroll
    for (int nb = 0; nb < 8; ++nb) b1v[nb] = b1[nb * 16 + l15];
    float b2v[16];
#pragma unroll
    for (int nb = 0; nb < 16; ++nb) b2v[nb] = b2[nb * 16 + l15];

    // ---- GEMM1: h = tanh(x @ W1^T + b1)  (16x64x128); all 16 B-frags preloaded ----
    short8 aw[16];
#pragma unroll
    for (int h = 0; h < 16; ++h)
        aw[h] = *(const short8*)(wa + ((h >> 1) * 16 + l15) * DD + (h & 1) * 32 + q * 8);

    unsigned g1p[16];   // packed bf16 (1-h^2), pairs over i: g1p[nb*2+(i>>1)]
#pragma unroll
    for (int nb = 0; nb < 8; ++nb) {
        float4v acc = {0.f, 0.f, 0.f, 0.f};
        acc = __builtin_amdgcn_mfma_f32_16x16x32_bf16(ax[0], aw[nb * 2 + 0], acc, 0, 0, 0);
        acc = __builtin_amdgcn_mfma_f32_16x16x32_bf16(ax[1], aw[nb * 2 + 1], acc, 0, 0, 0);
        int c = nb * 16 + l15;
#pragma unroll
        for (int i = 0; i < 4; i += 2) {
            float h0 = ftanh(acc[i]     + b1v[nb]);
            float h1 = ftanh(acc[i + 1] + b1v[nb]);
            h_s[q * 4 + i][c]     = f2b(h0);
            h_s[q * 4 + i + 1][c] = f2b(h1);
            g1p[nb * 2 + (i >> 1)] = (unsigned)f2b(1.f - h0 * h0)
                                   | ((unsigned)f2b(1.f - h1 * h1) << 16);
        }
    }

    // preload GEMM2 pair-0 B-frags BEFORE the fence (stays in flight across it)
    short8 bwA[8], bwB[8];
#pragma unroll
    for (int h = 0; h < 8; ++h)
        bwA[h] = *(const short8*)(wb + ((h >> 2) * 16 + l15) * TWOD + (h & 3) * 32 + q * 8);

    lds_fence();   // h_s, v_s visible wave-wide

    // ---- GEMM2: u = tanh(h @ W2^T + b2)  (16x128x256), fused y partials ----
    short8 ha[4];
#pragma unroll
    for (int kb = 0; kb < 4; ++kb)
        ha[kb] = *(const short8*)(&h_s[l15][kb * 32 + q * 8]);

    float yp[4] = {0.f, 0.f, 0.f, 0.f};
#pragma unroll
    for (int p = 0; p < 8; ++p) {
        short8* cur = (p & 1) ? bwB : bwA;
        short8* nxt = (p & 1) ? bwA : bwB;
        if (p < 7) {
#pragma unroll
            for (int h = 0; h < 8; ++h)
                nxt[h] = *(const short8*)(wb + (((p + 1) * 2 + (h >> 2)) * 16 + l15) * TWOD
                                          + (h & 3) * 32 + q * 8);
        }
#pragma unroll
        for (int s = 0; s < 2; ++s) {
            const int nb = p * 2 + s;
            float4v acc = {0.f, 0.f, 0.f, 0.f};
#pragma unroll
            for (int kb = 0; kb < 4; ++kb)
                acc = __builtin_amdgcn_mfma_f32_16x16x32_bf16(ha[kb], cur[s * 4 + kb], acc, 0, 0, 0);
            const int n = nb * 16 + l15;
#pragma unroll
            for (int i = 0; i < 4; ++i) {
                const int r = q * 4 + i;
                float u = ftanh(acc[i] + b2v[nb]);
                d_s[r][n] = f2b(u);
                yp[i] += v_s[r][n >> 2] * u;
            }
        }
    }

    // complete y (each j=l15&3 summed over the 4 lanes sharing it within the quad-row group)
#pragma unroll
    for (int i = 0; i < 4; ++i) {
        yp[i] += __shfl_xor(yp[i], 4, 64);
        yp[i] += __shfl_xor(yp[i], 8, 64);
    }
    if (l15 < 4) {
#pragma unroll
        for (int i = 0; i < 4; ++i)
            ((float*)&y_s[q * 4 + i])[l15] = yp[i];
    }

    // preload GEMM3 nb=0 B-frags before the fence
    short8 cwA[8], cwB[8];
#pragma unroll
    for (int kb = 0; kb < 8; ++kb)
        cwA[kb] = *(const short8*)(wc + l15 * RD + kb * 32 + q * 8);

    lds_fence();   // u (d_s), y_s visible

    // ---- fused mid-pass: per row, lane l owns cells n=4l..4l+3 of u ----
    //   dv_l = 2*sum_j y_j*u[4l+j]  -> out (coalesced)
    //   da2[4l+j] = 2*y_j*v_l*(1-u^2) -> write back in place (same lane, same addr)
#pragma unroll
    for (int r = 0; r < 16; ++r) {
        ull uu = *(const ull*)(&d_s[r][4 * l]);
        float4v y = y_s[r];
        float vv = v_s[r][l];
        float u0 = b2f((unsigned short)uu);
        float u1 = b2f((unsigned short)(uu >> 16));
        float u2 = b2f((unsigned short)(uu >> 32));
        float u3 = b2f((unsigned short)(uu >> 48));
        float dvv = y.x * u0 + y.y * u1 + y.z * u2 + y.w * u3;
        out[(row0 + r) * TWOD + DD + l] = -2.0f * dvv;
        float t0 = 2.0f * y.x * vv * (1.0f - u0 * u0);
        float t1 = 2.0f * y.y * vv * (1.0f - u1 * u1);
        float t2 = 2.0f * y.z * vv * (1.0f - u2 * u2);
        float t3 = 2.0f * y.w * vv * (1.0f - u3 * u3);
        ull w = (ull)f2b(t0) | ((ull)f2b(t1) << 16) | ((ull)f2b(t2) << 32) | ((ull)f2b(t3) << 48);
        *(ull*)(&d_s[r][4 * l]) = w;
    }

    lds_fence();   // da2 visible

    // ---- GEMM3: dh = da2 @ W2  (16x256x128); da1 = dh*(1-h^2) -> h_s ----
    short8 da[8];
#pragma unroll
    for (int kb = 0; kb < 8; ++kb)
        da[kb] = *(const short8*)(&d_s[l15][kb * 32 + q * 8]);

#pragma unroll
    for (int nb = 0; nb < 8; ++nb) {
        short8* cur = (nb & 1) ? cwB : cwA;
        short8* nxt = (nb & 1) ? cwA : cwB;
        if (nb < 7) {
#pragma unroll
            for (int kb = 0; kb < 8; ++kb)
                nxt[kb] = *(const short8*)(wc + ((nb + 1) * 16 + l15) * RD + kb * 32 + q * 8);
        }
        float4v acc = {0.f, 0.f, 0.f, 0.f};
#pragma unroll
        for (int kb = 0; kb < 8; ++kb)
            acc = __builtin_amdgcn_mfma_f32_16x16x32_bf16(da[kb], cur[kb], acc, 0, 0, 0);
        const int c = nb * 16 + l15;
#pragma unroll
        for (int i = 0; i < 4; ++i) {
            unsigned short gh = (i & 1) ? (unsigned short)(g1p[nb * 2 + (i >> 1)] >> 16)
                                        : (unsigned short)(g1p[nb * 2 + (i >> 1)]);
            h_s[q * 4 + i][c] = f2b(acc[i] * b2f(gh));
        }
    }

    // preload all 16 GEMM4 B-frags before the fence
    short8 dw[16];
#pragma unroll
    for (int h = 0; h < 16; ++h)
        dw[h] = *(const short8*)(wd + ((h >> 2) * 16 + l15) * TWOD + (h & 3) * 32 + q * 8);

    lds_fence();   // da1 visible

    // ---- GEMM4: dx = da1 @ W1  (16x128x64) -> out[:, :64] ----
    short8 dfa[4];
#pragma unroll
    for (int kb = 0; kb < 4; ++kb)
        dfa[kb] = *(const short8*)(&h_s[l15][kb * 32 + q * 8]);
#pragma unroll
    for (int nb = 0; nb < 4; ++nb) {
        float4v acc = {0.f, 0.f, 0.f, 0.f};
#pragma unroll
        for (int kb = 0; kb < 4; ++kb)
            acc = __builtin_amdgcn_mfma_f32_16x16x32_bf16(dfa[kb], dw[nb * 4 + kb], acc, 0, 0, 0);
#pragma unroll
        for (int i = 0; i < 4; ++i)
            out[(row0 + q * 4 + i) * TWOD + nb * 16 + l15] = acc[i];
    }
}

extern "C" void kernel_launch(void* const* d_in, const int* in_sizes, int n_in,
                              void* d_out, int out_size, void* d_ws, size_t ws_size,
                              hipStream_t stream) {
    const float* inp = (const float*)d_in[1];
    const float* W1  = (const float*)d_in[2];
    const float* b1  = (const float*)d_in[3];
    const float* W2  = (const float*)d_in[4];
    const float* b2  = (const float*)d_in[5];

    unsigned short* wa = (unsigned short*)d_ws;
    unsigned short* wd = wa + 8192;
    unsigned short* wb = wd + 8192;
    unsigned short* wc = wb + 32768;

    prep_weights<<<128, 256, 0, stream>>>(W1, W2, wa, wd, wb, wc);

    const int rows = in_sizes[1] / TWOD;
    geognn_kernel<<<rows / 16, 64, 0, stream>>>(inp, b1, b2, wa, wd, wb, wc,
                                                (float*)d_out);
}